// Round 6
// baseline (191.130 us; speedup 1.0000x reference)
//
#include <hip/hip_runtime.h>
#include <hip/hip_cooperative_groups.h>

namespace cg = cooperative_groups;

namespace {
constexpr int kV     = 21;
constexpr int kInner = 1344 * 256;   // 344064 floats per n

typedef float f32x4 __attribute__((ext_vector_type(4)));

// workspace layout (float offsets; M doubles, 8B aligned)
constexpr int X4_OFF = 0;                       // [64][3][4][21] = 16128 floats
constexpr int M_OFF  = 16384;                   // [5376][9] doubles
constexpr int ST_OFF = M_OFF + 5376 * 9 * 2;    // [1344][2] floats

union SMem {
  struct { float ls[3][1344]; float part[252]; } p1;      // 17136 B
  struct { float Sld[64 * 65]; float At[3 * 462]; } p3;   // 22184 B
  struct { float S[32 * 64]; float uld[672 * 4]; } p7;    // 18944 B
};
}

// ---------------------------------------------------------------------------
// Single fused cooperative kernel. 512 blocks x 256 threads.
// ---------------------------------------------------------------------------
__global__ __launch_bounds__(256, 2) void fused_all(
    const float* __restrict__ x, const float* __restrict__ A,
    const float* __restrict__ W, const float* __restrict__ bias,
    const float* __restrict__ W_emb, const float* __restrict__ b_emb,
    const float* __restrict__ pos, const float* __restrict__ gamma,
    const float* __restrict__ beta, float* __restrict__ out,
    float* __restrict__ x4, double* __restrict__ M,
    float* __restrict__ stats) {
  cg::grid_group grid = cg::this_grid();
  __shared__ SMem sm;
  int b = blockIdx.x;
  int tid = threadIdx.x;

  // ---- phase 1: x4[n][ci][q][v] = sum over 64 t ----
  if (b < 256) {
    int n = b >> 2, q = b & 3;
    for (int idx = tid; idx < 1008; idx += 256) {
      int ci = idx / 336;
      int off = idx - ci * 336;
      ((f32x4*)sm.p1.ls)[idx] =
          ((const f32x4*)(x + (n * 3 + ci) * 5376 + q * 1344))[off];
    }
    __syncthreads();
    if (tid < 252) {
      int ci = tid / 84, rest = tid - ci * 84;
      int tq = rest / 21, v = rest - tq * 21;
      float s = 0.f;
#pragma unroll
      for (int i = 0; i < 16; ++i) s += sm.p1.ls[ci][(tq * 16 + i) * 21 + v];
      sm.p1.part[tid] = s;
    }
    __syncthreads();
    if (tid < 63) {
      int ci = tid / 21, v = tid - ci * 21;
      const float* p = sm.p1.part + ci * 84 + v;
      x4[((n * 3 + ci) * 4 + q) * 21 + v] = p[0] + p[21] + p[42] + p[63];
    }
  }
  grid.sync();

  // ---- phase 2: per-(r,w) moments over n -> M ----
  if (b < 256) {
    int r = b;
    for (int t = tid; t < 1323; t += 256) {     // At[k][w][v] = A[k][v][w]
      int k = t / 441, rem = t - k * 441;
      int v = rem / 21, w = rem - v * 21;
      sm.p3.At[k * 462 + w * 22 + v] = A[t];
    }
    for (int idx = tid; idx < 4032; idx += 256) {
      int n = idx / 63, kv = idx - n * 63;
      int k = kv / 21, v = kv - k * 21;
      int g = r * 3 + k, o = g >> 2, q = g & 3;
      const float* xp = x4 + n * 252 + q * 21 + v;
      sm.p3.Sld[n * 65 + kv] = W[o * 3 + 0] * xp[0] + W[o * 3 + 1] * xp[84] +
                               W[o * 3 + 2] * xp[168] + 64.f * bias[o];
    }
    __syncthreads();
    int lane = tid & 63, wg = tid >> 6;
    for (int w = wg; w < 21; w += 4) {
      float u[3];
#pragma unroll
      for (int k = 0; k < 3; ++k) {
        const float* a = sm.p3.At + k * 462 + w * 22;
        const float* s = sm.p3.Sld + lane * 65 + k * 21;
        float acc = 0.f;
#pragma unroll
        for (int v = 0; v < 21; ++v) acc += a[v] * s[v];
        u[k] = acc;
      }
      double u0 = u[0], u1 = u[1], u2 = u[2];
      double m[9] = {u0 * u0, u0 * u1, u0 * u2, u1 * u1, u1 * u2,
                     u2 * u2, u0,      u1,      u2};
#pragma unroll
      for (int off = 1; off < 64; off <<= 1) {
#pragma unroll
        for (int i = 0; i < 9; ++i) m[i] += __shfl_xor(m[i], off);
      }
      if (lane == 0) {
#pragma unroll
        for (int i = 0; i < 9; ++i) M[(r * 21 + w) * 9 + i] = m[i];
      }
    }
  }
  grid.sync();

  // ---- phase 3: BN stats per channel ----
  if (b < 336) {
    int ch = b * 4 + (tid >> 6);
    int co = tid & 63;
    double we0 = W_emb[co * 3 + 0], we1 = W_emb[co * 3 + 1],
           we2 = W_emb[co * 3 + 2];
    double be = b_emb[co];
    double S1 = 0.0, S2 = 0.0;
#pragma unroll
    for (int j = 0; j < 4; ++j) {
      int t6 = ch * 4 + j;
      int w = t6 % 21;
      const double* m = M + t6 * 9;
      double c = be + (double)pos[w * 64 + co];
      double lin = we0 * m[6] + we1 * m[7] + we2 * m[8];
      S1 += lin + 64.0 * c;
      S2 += we0 * we0 * m[0] + 2.0 * we0 * we1 * m[1] + 2.0 * we0 * we2 * m[2] +
            we1 * we1 * m[3] + 2.0 * we1 * we2 * m[4] + we2 * we2 * m[5] +
            2.0 * c * lin + 64.0 * c * c;
    }
#pragma unroll
    for (int off = 1; off < 64; off <<= 1) {
      S1 += __shfl_xor(S1, off);
      S2 += __shfl_xor(S2, off);
    }
    if (co == 0) {
      double mean = S1 * (1.0 / 16384.0);
      double var = S2 * (1.0 / 16384.0) - mean * mean;
      double inv = rsqrt(var + 1e-5);
      stats[ch * 2 + 0] = (float)((double)gamma[ch] * inv);
      stats[ch * 2 + 1] = (float)((double)beta[ch] - mean * (double)gamma[ch] * inv);
    }
  }
  grid.sync();

  // ---- phase 4: epilogue. block b: n = b>>3, r-chunk = b&7 (32 r's) ----
  {
    int n = b >> 3, rc = b & 7;
    int r0 = rc * 32;
    for (int idx = tid; idx < 2016; idx += 256) {   // S for 32 r's
      int rr = idx / 63, kv = idx - rr * 63;
      int k = kv / 21, v = kv - k * 21;
      int g = (r0 + rr) * 3 + k, o = g >> 2, q = g & 3;
      const float* xp = x4 + n * 252 + q * 21 + v;
      sm.p7.S[rr * 64 + kv] = W[o * 3 + 0] * xp[0] + W[o * 3 + 1] * xp[84] +
                              W[o * 3 + 2] * xp[168] + 64.f * bias[o];
    }
    __syncthreads();
    for (int idx = tid; idx < 2016; idx += 256) {   // u for 672 t6 groups
      int t6l = idx / 3, k = idx - t6l * 3;
      int rr = t6l / 21, w = t6l - rr * 21;
      const float* a = A + k * 441 + w;             // stride 21 over v
      const float* s = sm.p7.S + rr * 64 + k * 21;
      float acc = 0.f;
#pragma unroll
      for (int v = 0; v < 21; ++v) acc += a[v * 21] * s[v];
      sm.p7.uld[t6l * 4 + k] = acc;
    }
    __syncthreads();
    size_t base = (size_t)n * kInner + rc * 43008;
    int ch_base = rc * 168;
    for (int it = 0; it < 42; ++it) {
      int off = it * 1024 + tid * 4;
      int t6l = off >> 6;
      int co = off & 63;                            // 4-aligned
      int w = t6l % 21;
      int ch = ch_base + (off >> 8);
      float u0 = sm.p7.uld[t6l * 4 + 0], u1 = sm.p7.uld[t6l * 4 + 1],
            u2 = sm.p7.uld[t6l * 4 + 2];
      float sc = stats[ch * 2 + 0], sh = stats[ch * 2 + 1];
      f32x4 o;
#pragma unroll
      for (int d = 0; d < 4; ++d) {
        const float* we = W_emb + (co + d) * 3;
        o[d] = (we[0] * u0 + we[1] * u1 + we[2] * u2 + b_emb[co + d] +
                pos[w * 64 + co + d]) * sc + sh;
      }
      __builtin_nontemporal_store(o, (f32x4*)(out + base + off));
    }
  }
}

extern "C" void kernel_launch(void* const* d_in, const int* in_sizes, int n_in,
                              void* d_out, int out_size, void* d_ws, size_t ws_size,
                              hipStream_t stream) {
  const float* x      = (const float*)d_in[0];
  const float* A      = (const float*)d_in[1];
  const float* conv_w = (const float*)d_in[2];
  const float* conv_b = (const float*)d_in[3];
  const float* W_emb  = (const float*)d_in[4];
  const float* b_emb  = (const float*)d_in[5];
  const float* pos    = (const float*)d_in[6];
  const float* gamma  = (const float*)d_in[7];
  const float* beta   = (const float*)d_in[8];
  float* out = (float*)d_out;
  float* ws  = (float*)d_ws;

  float*  x4    = ws + X4_OFF;
  double* M     = (double*)(ws + M_OFF);
  float*  stats = ws + ST_OFF;

  void* args[] = {&x, &A, &conv_w, &conv_b, &W_emb, &b_emb, &pos,
                  &gamma, &beta, &out, &x4, &M, &stats};
  hipLaunchCooperativeKernel((void*)fused_all, dim3(512), dim3(256), args, 0,
                             stream);
}

// Round 7
// 68.513 us; speedup vs baseline: 2.7897x; 2.7897x over previous
//
#include <hip/hip_runtime.h>

namespace {
constexpr int kV     = 21;
constexpr int kInner = 1344 * 256;   // 344064 floats per n

typedef float f32x4 __attribute__((ext_vector_type(4)));

// workspace layout (floats)
constexpr int X4_OFF = 0;            // [64][3][4][21] = 16128 floats
constexpr int ST_OFF = 16384;        // [1344][2] floats
}

// ---------------------------------------------------------------------------
// kA: X4[n][ci][q][v] = sum_{t=q*64..q*64+63} x[n][ci][t][v]
// one block per (n,q): coalesced f32x4 loads -> LDS -> 2-stage reduce
// ---------------------------------------------------------------------------
__global__ __launch_bounds__(256) void kA_x4(const float* __restrict__ x,
                                             float* __restrict__ x4) {
  __shared__ float ls[3][1344];
  __shared__ float part[252];
  int b = blockIdx.x;                 // 256 blocks
  int n = b >> 2, q = b & 3;
  int tid = threadIdx.x;
  for (int idx = tid; idx < 1008; idx += 256) {   // 1008 f32x4 total
    int ci = idx / 336;
    int off = idx - ci * 336;
    ((f32x4*)ls)[idx] =
        ((const f32x4*)(x + (n * 3 + ci) * 5376 + q * 1344))[off];
  }
  __syncthreads();
  if (tid < 252) {
    int ci = tid / 84, rest = tid - ci * 84;
    int tq = rest / 21, v = rest - tq * 21;
    float s = 0.f;
#pragma unroll
    for (int i = 0; i < 16; ++i) s += ls[ci][(tq * 16 + i) * 21 + v];
    part[tid] = s;
  }
  __syncthreads();
  if (tid < 63) {
    int ci = tid / 21, v = tid - ci * 21;
    const float* p = part + ci * 84 + v;
    x4[((n * 3 + ci) * 4 + q) * 21 + v] = p[0] + p[21] + p[42] + p[63];
  }
}

// ---------------------------------------------------------------------------
// kB_stats: one block per BN channel ch. In-block:
//  (A) S[rr][n][k*21+v] in LDS (pitch 65, conflict-free) for the <=2 r's
//  (B) thread (j=tid>>6, n=tid&63): u[k] = sum_v A[k][v][w]*S, t6 = ch*4+j
//      -> 9 double moments, shuffle-xor over n (wave) -> md[j]
//  (C) thread (j, co=n): quadratic form -> S1,S2; reduce; stats[ch]
// ---------------------------------------------------------------------------
__global__ __launch_bounds__(256) void kB_stats(
    const float* __restrict__ x4, const float* __restrict__ A,
    const float* __restrict__ W, const float* __restrict__ bias,
    const float* __restrict__ W_emb, const float* __restrict__ b_emb,
    const float* __restrict__ pos, const float* __restrict__ gamma,
    const float* __restrict__ beta, float* __restrict__ stats) {
  __shared__ float S[2][64][65];
  __shared__ double md[4][9];
  __shared__ double red[2][4];
  int ch = blockIdx.x;
  int tid = threadIdx.x;
  int t6_0 = ch * 4;
  int r0 = t6_0 / 21;
  int nR = (t6_0 + 3) / 21 - r0 + 1;    // 1 or 2
  // phase A
  for (int idx = tid; idx < nR * 4032; idx += 256) {
    int rr = idx / 4032, rem = idx - rr * 4032;
    int n = rem / 63, kv = rem - n * 63;
    int k = kv / 21, v = kv - k * 21;
    int g = (r0 + rr) * 3 + k, o = g >> 2, q = g & 3;
    const float* xp = x4 + n * 252 + q * 21 + v;
    S[rr][n][kv] = W[o * 3 + 0] * xp[0] + W[o * 3 + 1] * xp[84] +
                   W[o * 3 + 2] * xp[168] + 64.f * bias[o];
  }
  __syncthreads();
  // phase B
  int j = tid >> 6, n = tid & 63;
  int t6 = t6_0 + j;
  int r = t6 / 21, w = t6 - r * 21;
  int rr = r - r0;
  double u0, u1, u2;
  {
    float uu[3];
#pragma unroll
    for (int k = 0; k < 3; ++k) {
      const float* a = A + k * 441 + w;          // stride 21 over v (wave-uniform)
      const float* s = &S[rr][n][k * 21];
      float acc = 0.f;
#pragma unroll
      for (int v = 0; v < 21; ++v) acc += a[v * 21] * s[v];
      uu[k] = acc;
    }
    u0 = uu[0]; u1 = uu[1]; u2 = uu[2];
  }
  double m[9] = {u0 * u0, u0 * u1, u0 * u2, u1 * u1, u1 * u2,
                 u2 * u2, u0,      u1,      u2};
#pragma unroll
  for (int off = 1; off < 64; off <<= 1) {
#pragma unroll
    for (int i = 0; i < 9; ++i) m[i] += __shfl_xor(m[i], off);
  }
  if (n == 0) {
#pragma unroll
    for (int i = 0; i < 9; ++i) md[j][i] = m[i];
  }
  __syncthreads();
  // phase C: thread (j, co = n)
  int co = n;
  double we0 = W_emb[co * 3 + 0], we1 = W_emb[co * 3 + 1],
         we2 = W_emb[co * 3 + 2];
  double c = (double)b_emb[co] + (double)pos[w * 64 + co];
  const double* mm = md[j];
  double lin = we0 * mm[6] + we1 * mm[7] + we2 * mm[8];
  double S1 = lin + 64.0 * c;
  double S2 = we0 * we0 * mm[0] + 2.0 * we0 * we1 * mm[1] +
              2.0 * we0 * we2 * mm[2] + we1 * we1 * mm[3] +
              2.0 * we1 * we2 * mm[4] + we2 * we2 * mm[5] +
              2.0 * c * lin + 64.0 * c * c;
#pragma unroll
  for (int off = 1; off < 64; off <<= 1) {
    S1 += __shfl_xor(S1, off);
    S2 += __shfl_xor(S2, off);
  }
  if (co == 0) { red[0][j] = S1; red[1][j] = S2; }
  __syncthreads();
  if (tid == 0) {
    double T1 = red[0][0] + red[0][1] + red[0][2] + red[0][3];
    double T2 = red[1][0] + red[1][1] + red[1][2] + red[1][3];
    double mean = T1 * (1.0 / 16384.0);
    double var = T2 * (1.0 / 16384.0) - mean * mean;
    double inv = rsqrt(var + 1e-5);
    stats[ch * 2 + 0] = (float)((double)gamma[ch] * inv);
    stats[ch * 2 + 1] = (float)((double)beta[ch] - mean * (double)gamma[ch] * inv);
  }
}

// ---------------------------------------------------------------------------
// kC: epilogue. One block per (n, 2048-inner chunk). Recomputes the <=3
// S-rows and 32 u-triples in LDS from x4, then 8 outputs/thread, NT stores.
// ---------------------------------------------------------------------------
__global__ __launch_bounds__(256) void kC_out(
    const float* __restrict__ x4, const float* __restrict__ A,
    const float* __restrict__ W, const float* __restrict__ bias,
    const float* __restrict__ W_emb, const float* __restrict__ b_emb,
    const float* __restrict__ pos, const float* __restrict__ stats,
    float* __restrict__ out) {
  __shared__ float Sld[3 * 64];      // S[rr][k*21+v]
  __shared__ float uld[32 * 4];      // u[t6_local][k]
  int b = blockIdx.x;                // 10752
  int n = b / 168;
  int bi = b - n * 168;
  int tid = threadIdx.x;
  int base = bi * 32;                // first t6
  int r0 = base / 21;
  int nR = (base + 31) / 21 - r0 + 1;   // <= 3
  // phase 1: S rows for nR r's
  if (tid < nR * 63) {
    int rr = tid / 63, kv = tid - rr * 63;
    int k = kv / 21, v = kv - k * 21;
    int g = (r0 + rr) * 3 + k;
    int o = g >> 2, q = g & 3;
    const float* xp = x4 + n * 252 + q * 21 + v;
    Sld[rr * 64 + kv] = W[o * 3 + 0] * xp[0] + W[o * 3 + 1] * xp[84] +
                        W[o * 3 + 2] * xp[168] + 64.f * bias[o];
  }
  __syncthreads();
  // phase 2: u for 32 t6 groups
  if (tid < 96) {
    int t6l = tid / 3, k = tid - t6l * 3;
    int t6 = base + t6l;
    int r = t6 / 21;
    int w = t6 - r * 21;
    const float* a = A + k * 441 + w;          // stride 21 over v
    const float* s = Sld + (r - r0) * 64 + k * 21;
    float acc = 0.f;
#pragma unroll
    for (int v = 0; v < 21; ++v) acc += a[v * 21] * s[v];
    uld[t6l * 4 + k] = acc;
  }
  __syncthreads();
  // phase 3: 8 outputs/thread
  int t6l = tid >> 3;
  int t6 = base + t6l;
  int w = t6 % 21;
  int co = (tid & 7) * 8;
  int ch = bi * 8 + (tid >> 5);
  int inner0 = bi * 2048 + tid * 8;
  float u0 = uld[t6l * 4 + 0], u1 = uld[t6l * 4 + 1], u2 = uld[t6l * 4 + 2];
  float sc = stats[ch * 2 + 0], sh = stats[ch * 2 + 1];
  float res[8];
#pragma unroll
  for (int d = 0; d < 8; ++d) {
    const float* we = W_emb + (co + d) * 3;
    res[d] = (we[0] * u0 + we[1] * u1 + we[2] * u2 + b_emb[co + d] +
              pos[w * 64 + co + d]) * sc + sh;
  }
  float* outp = out + (size_t)n * kInner + inner0;
  f32x4 o0 = {res[0], res[1], res[2], res[3]};
  f32x4 o1 = {res[4], res[5], res[6], res[7]};
  __builtin_nontemporal_store(o0, (f32x4*)outp);
  __builtin_nontemporal_store(o1, (f32x4*)outp + 1);
}

extern "C" void kernel_launch(void* const* d_in, const int* in_sizes, int n_in,
                              void* d_out, int out_size, void* d_ws, size_t ws_size,
                              hipStream_t stream) {
  const float* x      = (const float*)d_in[0];
  const float* A      = (const float*)d_in[1];
  const float* conv_w = (const float*)d_in[2];
  const float* conv_b = (const float*)d_in[3];
  const float* W_emb  = (const float*)d_in[4];
  const float* b_emb  = (const float*)d_in[5];
  const float* pos    = (const float*)d_in[6];
  const float* gamma  = (const float*)d_in[7];
  const float* beta   = (const float*)d_in[8];
  float* out = (float*)d_out;
  float* ws  = (float*)d_ws;

  float* x4    = ws + X4_OFF;
  float* stats = ws + ST_OFF;

  kA_x4<<<256, 256, 0, stream>>>(x, x4);
  kB_stats<<<1344, 256, 0, stream>>>(x4, A, conv_w, conv_b, W_emb, b_emb, pos,
                                     gamma, beta, stats);
  kC_out<<<10752, 256, 0, stream>>>(x4, A, conv_w, conv_b, W_emb, b_emb, pos,
                                    stats, out);
}